// Round 8
// baseline (164.266 us; speedup 1.0000x reference)
//
#include <hip/hip_runtime.h>
#include <math.h>

// Dims (fixed by the problem)
#define B_SZ 2
#define L_SZ 384
#define D_SZ 384
#define S_SZ 384
#define BLK_ELEMS (L_SZ * D_SZ)        // 147456 per batch
#define TOT_ELEMS (B_SZ * L_SZ * D_SZ) // 294912
#define LOG2E 1.4426950408889634f

typedef __attribute__((ext_vector_type(8))) short bf16x8;
typedef __attribute__((ext_vector_type(4))) float f32x4;

__device__ __forceinline__ float fexp2(float x) {
  return __builtin_amdgcn_exp2f(x);
}
__device__ __forceinline__ float softplus_f(float z) {
  return (z > 20.f) ? z : log1pf(__expf(z));
}
__device__ __forceinline__ unsigned short f2bf(float f) {  // RNE f32->bf16
  unsigned int u = __float_as_uint(f);
  return (unsigned short)((u + 0x7FFFu + ((u >> 16) & 1u)) >> 16);
}
// Compiler scheduling fence (stops prefetch-load sinking; R4-R6 lesson).
#define PIPELINE_FENCE() asm volatile("" ::: "memory")

// ---------------------------------------------------------------------------
// Convert x, dt_w, B_w, C_w to bf16. Block-segmented so no per-thread branch.
// ---------------------------------------------------------------------------
__global__ __launch_bounds__(256) void cvt_bf16_kernel(
    const float* __restrict__ x, const float* __restrict__ dt_w,
    const float* __restrict__ B_w, const float* __restrict__ C_w,
    unsigned short* __restrict__ xbf, unsigned short* __restrict__ dtwbf,
    unsigned short* __restrict__ Bwbf, unsigned short* __restrict__ Cwbf) {
  const int blk = blockIdx.x;
  const float* src;
  unsigned short* dst;
  int base;
  if (blk < 288) { src = x; dst = xbf; base = blk; }
  else if (blk < 432) { src = dt_w; dst = dtwbf; base = blk - 288; }
  else if (blk < 576) { src = B_w; dst = Bwbf; base = blk - 432; }
  else { src = C_w; dst = Cwbf; base = blk - 576; }
  const int idx = base * 1024 + threadIdx.x * 4;
  const float4 v = *(const float4*)(src + idx);
  ushort4 o;
  o.x = f2bf(v.x); o.y = f2bf(v.y); o.z = f2bf(v.z); o.w = f2bf(v.w);
  *(ushort4*)(dst + idx) = o;
}

// ---------------------------------------------------------------------------
// Barrier-free dual MFMA NT-GEMM. ONE WAVE PER BLOCK (64 thr, grid 1152):
// removes any intra-block coupling, and __launch_bounds__(64,2) grants a
// 256-VGPR budget so the 36-fragment burst (144 VGPR) provably fits.
// No fence: compiler interleaves loads with MFMAs using fine vmcnt.
// Layouts (m89/m91-verified): A/B frag = [lane&15][quad*8+j]; C/D:
// col=lane&15, row=quad*4+reg.
// MODE 1: O1 = softplus(acc1+bias) f32, O2 = bf16(acc2)  [dt, x_dbl]
// MODE 2: O1 = acc1 f32, O2 = acc2 f32                   [Bm, Cm]
// ---------------------------------------------------------------------------
template <int MODE>
__global__ __launch_bounds__(64, 2) void mfma_dual_gemm(
    const unsigned short* __restrict__ Abf,
    const unsigned short* __restrict__ W1bf,
    const unsigned short* __restrict__ W2bf,
    const float* __restrict__ bias,
    float* __restrict__ O1, void* __restrict__ O2v) {
  const int wid = blockIdx.x;     // 0..1151, one wave per block
  const int mt = wid / 24;        // 0..47
  const int nt = wid - mt * 24;   // 0..23
  const int lane = threadIdx.x;   // 0..63
  const int rc = lane & 15;
  const int quad = lane >> 4;

  const unsigned short* ap = Abf + (mt * 16 + rc) * 384 + quad * 8;
  const unsigned short* w1p = W1bf + (nt * 16 + rc) * 384 + quad * 8;
  const unsigned short* w2p = W2bf + (nt * 16 + rc) * 384 + quad * 8;

  bf16x8 af[12], w1f[12], w2f[12];
#pragma unroll
  for (int kt = 0; kt < 12; ++kt) {
    af[kt] = *(const bf16x8*)(ap + kt * 32);
    w1f[kt] = *(const bf16x8*)(w1p + kt * 32);
    w2f[kt] = *(const bf16x8*)(w2p + kt * 32);
  }
  f32x4 acc1 = {0.f, 0.f, 0.f, 0.f};
  f32x4 acc2 = {0.f, 0.f, 0.f, 0.f};
#pragma unroll
  for (int kt = 0; kt < 12; ++kt) {
    acc1 = __builtin_amdgcn_mfma_f32_16x16x32_bf16(af[kt], w1f[kt], acc1, 0, 0, 0);
    acc2 = __builtin_amdgcn_mfma_f32_16x16x32_bf16(af[kt], w2f[kt], acc2, 0, 0, 0);
  }
  const int col = nt * 16 + rc;
  const int row0 = mt * 16 + quad * 4;
  if constexpr (MODE == 1) {
    unsigned short* O2 = (unsigned short*)O2v;
    const float bb = bias[col];
#pragma unroll
    for (int r = 0; r < 4; ++r) {
      O1[(row0 + r) * 384 + col] = softplus_f(acc1[r] + bb);
      O2[(row0 + r) * 384 + col] = f2bf(acc2[r]);
    }
  } else {
    float* O2 = (float*)O2v;
#pragma unroll
    for (int r = 0; r < 4; ++r) {
      O1[(row0 + r) * 384 + col] = acc1[r];
      O2[(row0 + r) * 384 + col] = acc2[r];
    }
  }
}

// ---------------------------------------------------------------------------
// Conv + SiLU + transpose: u[b,l,i] (coalesced) plus dt_t[b,i,l],
// dtu_t[b,i,l] via 32x32 LDS transpose (scan reads dt/dtu contiguously).
// ---------------------------------------------------------------------------
__global__ __launch_bounds__(256) void conv_tr_kernel(
    const float* __restrict__ x, const float* __restrict__ cw,
    const float* __restrict__ cb, const float* __restrict__ dt,
    float* __restrict__ u, float* __restrict__ dt_t,
    float* __restrict__ dtu_t) {
  __shared__ float Tdt[32][33];
  __shared__ float Tdu[32][33];
  const int tx = threadIdx.x;   // 0..31
  const int ty = threadIdx.y;   // 0..7
  const int b = blockIdx.z;
  const int i0 = blockIdx.y * 32;
  const int l0 = blockIdx.x * 32;
  const int gi = i0 + tx;
  const float cbv = cb[gi];
  const float cw0 = cw[gi * 4 + 0], cw1 = cw[gi * 4 + 1];
  const float cw2 = cw[gi * 4 + 2], cw3 = cw[gi * 4 + 3];
#pragma unroll
  for (int r = 0; r < 4; ++r) {
    const int l = l0 + ty + 8 * r;
    float acc = cbv;
    const float x3 = x[(b * L_SZ + l) * D_SZ + gi];
    const float x2 = (l >= 1) ? x[(b * L_SZ + l - 1) * D_SZ + gi] : 0.f;
    const float x1 = (l >= 2) ? x[(b * L_SZ + l - 2) * D_SZ + gi] : 0.f;
    const float x0 = (l >= 3) ? x[(b * L_SZ + l - 3) * D_SZ + gi] : 0.f;
    acc = fmaf(x0, cw0, acc);
    acc = fmaf(x1, cw1, acc);
    acc = fmaf(x2, cw2, acc);
    acc = fmaf(x3, cw3, acc);
    const float uv = acc / (1.f + __expf(-acc));
    const int off = (b * L_SZ + l) * D_SZ + gi;
    u[off] = uv;
    const float dtv = dt[off];
    Tdt[ty + 8 * r][tx] = dtv;
    Tdu[ty + 8 * r][tx] = dtv * uv;
  }
  __syncthreads();
#pragma unroll
  for (int r = 0; r < 4; ++r) {
    const int il = ty + 8 * r;
    const int off = (b * D_SZ + i0 + il) * L_SZ + l0 + tx;
    dt_t[off] = Tdt[tx][il];
    dtu_t[off] = Tdu[tx][il];
  }
}

// ---------------------------------------------------------------------------
// Selective scan v7: 6-way j-split (j = 64w + lane), 2304 waves per launch
// (two launches, one per batch, so GEMM dispatches surface in the profile).
// Triple-buffered register pipeline pinned by fences. load_chunk uses exact
// constant offsets (R7's dead per-element clamp cost 8 cmp+cndmask/chunk).
// Value-folding butterfly reduction; partials [w][b][i][l]; u*D in combine.
// ---------------------------------------------------------------------------
#define CH 8
__global__ __launch_bounds__(256, 4) void scan_kernel(
    const float* __restrict__ A_log, const float* __restrict__ dt_t,
    const float* __restrict__ dtu_t, const float* __restrict__ Bm,
    const float* __restrict__ Cm, float* __restrict__ part, int wave_base) {
  const int wid = wave_base + (((blockIdx.x << 8) + (int)threadIdx.x) >> 6);
  const int lane = threadIdx.x & 63;
  const int w = wid % 6;
  const int sid = wid / 6;
  const int b = sid / D_SZ;
  const int i = sid % D_SZ;
  const int j = w * 64 + lane;

  const float a2 = -__expf(A_log[i * S_SZ + j]) * LOG2E;
  const float bw = Bm[(b * D_SZ + i) * S_SZ + j];
  float h = 0.f;

  const float* dtp = dt_t + (b * D_SZ + i) * L_SZ;   // contiguous in l
  const float* dup = dtu_t + (b * D_SZ + i) * L_SZ;
  const float* cp = Cm + b * BLK_ELEMS + j;          // + l*D_SZ per step
  float* pp = part + ((w * B_SZ + b) * D_SZ + i) * L_SZ;

  const int sidx = ((lane & 1) << 2) | (lane & 2) | ((lane >> 2) & 1);
  const bool storer = lane < 8;

  float C0[8], D0[8], U0[8];
  float C1[8], D1[8], U1[8];
  float C2[8], D2[8], U2[8];

  auto load_chunk = [&](int c, float (&cx)[8], float (&dx)[8], float (&ux)[8]) {
    const float* dpc = dtp + c * CH;
    const float* upc = dup + c * CH;
    const float* cpc = cp + c * CH * D_SZ;
    *(float4*)&dx[0] = *(const float4*)(dpc);
    *(float4*)&dx[4] = *(const float4*)(dpc + 4);
    *(float4*)&ux[0] = *(const float4*)(upc);
    *(float4*)&ux[4] = *(const float4*)(upc + 4);
#pragma unroll
    for (int s = 0; s < CH; ++s) cx[s] = cpc[s * D_SZ];
  };

  auto compute_chunk = [&](int c, const float (&cx)[8], const float (&dx)[8],
                           const float (&ux)[8]) {
    float accs[8];
#pragma unroll
    for (int s = 0; s < CH; ++s) {
      const float e = fexp2(dx[s] * a2);
      h = fmaf(e, h, bw * ux[s]);
      accs[s] = h * cx[s];
    }
    // fold 8 values into lanes (bitrev3 target), then cross-group sum
    {
      const bool s1 = (lane & 1) != 0;
#pragma unroll
      for (int q = 0; q < 4; ++q) {
        const float keep = s1 ? accs[q + 4] : accs[q];
        const float send = s1 ? accs[q] : accs[q + 4];
        accs[q] = keep + __shfl_xor(send, 1, 64);
      }
      const bool s2 = (lane & 2) != 0;
#pragma unroll
      for (int q = 0; q < 2; ++q) {
        const float keep = s2 ? accs[q + 2] : accs[q];
        const float send = s2 ? accs[q] : accs[q + 2];
        accs[q] = keep + __shfl_xor(send, 2, 64);
      }
      const bool s3 = (lane & 4) != 0;
      {
        const float keep = s3 ? accs[1] : accs[0];
        const float send = s3 ? accs[0] : accs[1];
        accs[0] = keep + __shfl_xor(send, 4, 64);
      }
    }
    float r = accs[0];
    r += __shfl_xor(r, 8, 64);
    r += __shfl_xor(r, 16, 64);
    r += __shfl_xor(r, 32, 64);
    if (storer) pp[c * CH + sidx] = r;
  };

  load_chunk(0, C0, D0, U0);
  load_chunk(1, C1, D1, U1);
  for (int it = 0; it < 16; ++it) {
    const int c = 3 * it;
    load_chunk((c + 2 < 48) ? c + 2 : 47, C2, D2, U2);
    PIPELINE_FENCE();
    compute_chunk(c, C0, D0, U0);
    load_chunk((c + 3 < 48) ? c + 3 : 47, C0, D0, U0);
    PIPELINE_FENCE();
    compute_chunk(c + 1, C1, D1, U1);
    load_chunk((c + 4 < 48) ? c + 4 : 47, C1, D1, U1);
    PIPELINE_FENCE();
    compute_chunk(c + 2, C2, D2, U2);
  }
}

// ---------------------------------------------------------------------------
// Combine + transpose: y[b,l,i] = sum_w part[w][b][i][l] + u[b,l,i]*D[i]
// ---------------------------------------------------------------------------
__global__ __launch_bounds__(256) void combine_kernel(
    const float* __restrict__ part, const float* __restrict__ u,
    const float* __restrict__ Dv, float* __restrict__ y) {
  __shared__ float T[32][33];
  const int tx = threadIdx.x;        // 0..31
  const int ty0 = threadIdx.y;       // 0..7
  const int b = blockIdx.z;
  const int i0 = blockIdx.y * 32;
  const int l0 = blockIdx.x * 32;
#pragma unroll
  for (int r = 0; r < 4; ++r) {
    const int il = ty0 + 8 * r;
    float s = 0.f;
#pragma unroll
    for (int w = 0; w < 6; ++w)
      s += part[((w * B_SZ + b) * D_SZ + i0 + il) * L_SZ + l0 + tx];
    T[il][tx] = s;
  }
  __syncthreads();
#pragma unroll
  for (int r = 0; r < 4; ++r) {
    const int ll = ty0 + 8 * r;
    const int gi = i0 + tx;
    const int off = (b * L_SZ + l0 + ll) * D_SZ + gi;
    y[off] = fmaf(u[off], Dv[gi], T[tx][ll]);
  }
}

extern "C" void kernel_launch(void* const* d_in, const int* in_sizes, int n_in,
                              void* d_out, int out_size, void* d_ws,
                              size_t ws_size, hipStream_t stream) {
  const float* x = (const float*)d_in[0];
  const float* A_log = (const float*)d_in[1];
  const float* D = (const float*)d_in[2];
  const float* dt_w = (const float*)d_in[3];
  const float* dt_b = (const float*)d_in[4];
  const float* B_w = (const float*)d_in[5];
  const float* C_w = (const float*)d_in[6];
  const float* conv_w = (const float*)d_in[7];
  const float* conv_b = (const float*)d_in[8];
  float* y = (float*)d_out;

  float* ws = (float*)d_ws;
  float* dt = ws;                     // slot 0  [b,l,i]
  float* u = ws + TOT_ELEMS;          // slot 1
  float* Bm = ws + 2 * TOT_ELEMS;     // slot 2
  float* Cm = ws + 3 * TOT_ELEMS;     // slot 3
  float* dt_t = ws + 4 * TOT_ELEMS;   // slot 4  [b,i,l]
  float* dtu_t = ws + 5 * TOT_ELEMS;  // slot 5  [b,i,l]
  float* part = ws + 6 * TOT_ELEMS;   // slots 6..11  [w][b][i][l]
  // bf16 area after the 12 f32 slots (~14.2 MB + ~2.1 MB)
  unsigned short* bfarea = (unsigned short*)(ws + 12 * TOT_ELEMS);
  unsigned short* xbf = bfarea;                 // 294912
  unsigned short* dtwbf = bfarea + 294912;      // 147456
  unsigned short* Bwbf = bfarea + 442368;       // 147456
  unsigned short* Cwbf = bfarea + 589824;       // 147456
  unsigned short* xdblbf = bfarea + 737280;     // 294912

  cvt_bf16_kernel<<<720, 256, 0, stream>>>(x, dt_w, B_w, C_w, xbf, dtwbf, Bwbf, Cwbf);
  // GEMM1: dt = softplus(x·dt_w^T + b), x_dbl(bf16) = x·B_w^T
  mfma_dual_gemm<1><<<1152, 64, 0, stream>>>(xbf, dtwbf, Bwbf, dt_b, dt, xdblbf);
  // GEMM2: Bm = x_dbl·B_w^T, Cm = x_dbl·C_w^T
  mfma_dual_gemm<2><<<1152, 64, 0, stream>>>(xdblbf, Bwbf, Cwbf, nullptr, Bm, Cm);
  conv_tr_kernel<<<dim3(L_SZ / 32, D_SZ / 32, B_SZ), dim3(32, 8), 0, stream>>>(
      x, conv_w, conv_b, dt, u, dt_t, dtu_t);
  // scan split per batch (2 dispatches) so sub-scan kernels surface in top-5
  scan_kernel<<<576, 256, 0, stream>>>(A_log, dt_t, dtu_t, Bm, Cm, part, 0);
  scan_kernel<<<576, 256, 0, stream>>>(A_log, dt_t, dtu_t, Bm, Cm, part, 2304);
  combine_kernel<<<dim3(L_SZ / 32, D_SZ / 32, B_SZ), dim3(32, 8), 0, stream>>>(
      part, u, D, y);
}

// Round 9
// 148.833 us; speedup vs baseline: 1.1037x; 1.1037x over previous
//
#include <hip/hip_runtime.h>
#include <math.h>

// Dims (fixed by the problem)
#define B_SZ 2
#define L_SZ 384
#define D_SZ 384
#define S_SZ 384
#define BLK_ELEMS (L_SZ * D_SZ)        // 147456 per batch
#define TOT_ELEMS (B_SZ * L_SZ * D_SZ) // 294912
#define LOG2E 1.4426950408889634f

typedef __attribute__((ext_vector_type(8))) short bf16x8;
typedef __attribute__((ext_vector_type(4))) float f32x4;
typedef __attribute__((ext_vector_type(2))) float f32x2;

__device__ __forceinline__ float fexp2(float x) {
  return __builtin_amdgcn_exp2f(x);
}
__device__ __forceinline__ float softplus_f(float z) {
  return (z > 20.f) ? z : log1pf(__expf(z));
}
__device__ __forceinline__ unsigned short f2bf(float f) {  // RNE f32->bf16
  unsigned int u = __float_as_uint(f);
  return (unsigned short)((u + 0x7FFFu + ((u >> 16) & 1u)) >> 16);
}
#define PIPELINE_FENCE() asm volatile("" ::: "memory")

// ---------------------------------------------------------------------------
// Convert x, dt_w, B_w, C_w to bf16.
// ---------------------------------------------------------------------------
__global__ __launch_bounds__(256) void cvt_bf16_kernel(
    const float* __restrict__ x, const float* __restrict__ dt_w,
    const float* __restrict__ B_w, const float* __restrict__ C_w,
    unsigned short* __restrict__ xbf, unsigned short* __restrict__ dtwbf,
    unsigned short* __restrict__ Bwbf, unsigned short* __restrict__ Cwbf) {
  const int blk = blockIdx.x;
  const float* src;
  unsigned short* dst;
  int base;
  if (blk < 288) { src = x; dst = xbf; base = blk; }
  else if (blk < 432) { src = dt_w; dst = dtwbf; base = blk - 288; }
  else if (blk < 576) { src = B_w; dst = Bwbf; base = blk - 432; }
  else { src = C_w; dst = Cwbf; base = blk - 576; }
  const int idx = base * 1024 + threadIdx.x * 4;
  const float4 v = *(const float4*)(src + idx);
  ushort4 o;
  o.x = f2bf(v.x); o.y = f2bf(v.y); o.z = f2bf(v.z); o.w = f2bf(v.w);
  *(ushort4*)(dst + idx) = o;
}

// ---------------------------------------------------------------------------
// LDS-staged dual MFMA NT-GEMM. R6-R8's barrier-free version read fragments
// straight from global: each load = 16 lanes x 768-B-stride rows = 16 cache
// lines/instr -> ~35 us. Here: COALESCED staging (thread t loads contiguous
// byte 16*id of the strip), LDS redistribution (row pad +16 B: fragment
// reads are 2-way bank-aliased = free), ds_read_b128 fragments, 24 MFMAs.
// Tile M=32 x N=16, block 128 (2 waves), grid 24x24=576. LDS 50176 B.
// ---------------------------------------------------------------------------
template <int MODE>
__global__ __launch_bounds__(128, 2) void mfma_dual_gemm(
    const unsigned short* __restrict__ Abf,
    const unsigned short* __restrict__ W1bf,
    const unsigned short* __restrict__ W2bf,
    const float* __restrict__ bias,
    float* __restrict__ O1, void* __restrict__ O2v) {
  __shared__ unsigned short sA[32 * 392];   // rows padded 384->392 shorts
  __shared__ unsigned short sW1[16 * 392];
  __shared__ unsigned short sW2[16 * 392];

  const int t = threadIdx.x;      // 0..127
  const int wv = t >> 6;          // wave 0..1
  const int lane = t & 63;
  const int nt = blockIdx.x;      // 0..23
  const int mrow = blockIdx.y;    // 0..23 (M tile = 32 rows)

  const unsigned short* Ab = Abf + mrow * 32 * 384;
  const unsigned short* W1b = W1bf + nt * 16 * 384;
  const unsigned short* W2b = W2bf + nt * 16 * 384;

  // A strip: 32 rows x 48 b128-chunks = 1536 chunks; 12 per thread.
#pragma unroll
  for (int it = 0; it < 12; ++it) {
    const int id = t + it * 128;
    const int row = id / 48, col = id - row * 48;
    *(bf16x8*)&sA[row * 392 + col * 8] = *(const bf16x8*)(Ab + id * 8);
  }
  // W strips: 16 rows x 48 = 768 chunks; 6 per thread each.
#pragma unroll
  for (int it = 0; it < 6; ++it) {
    const int id = t + it * 128;
    const int row = id / 48, col = id - row * 48;
    *(bf16x8*)&sW1[row * 392 + col * 8] = *(const bf16x8*)(W1b + id * 8);
    *(bf16x8*)&sW2[row * 392 + col * 8] = *(const bf16x8*)(W2b + id * 8);
  }
  __syncthreads();

  const int rc = lane & 15;
  const int quad = lane >> 4;
  bf16x8 af[12], w1f[12], w2f[12];
#pragma unroll
  for (int kt = 0; kt < 12; ++kt) {
    af[kt] = *(const bf16x8*)&sA[(wv * 16 + rc) * 392 + quad * 8 + kt * 32];
    w1f[kt] = *(const bf16x8*)&sW1[rc * 392 + quad * 8 + kt * 32];
    w2f[kt] = *(const bf16x8*)&sW2[rc * 392 + quad * 8 + kt * 32];
  }
  PIPELINE_FENCE();
  f32x4 acc1 = {0.f, 0.f, 0.f, 0.f};
  f32x4 acc2 = {0.f, 0.f, 0.f, 0.f};
#pragma unroll
  for (int kt = 0; kt < 12; ++kt) {
    acc1 = __builtin_amdgcn_mfma_f32_16x16x32_bf16(af[kt], w1f[kt], acc1, 0, 0, 0);
    acc2 = __builtin_amdgcn_mfma_f32_16x16x32_bf16(af[kt], w2f[kt], acc2, 0, 0, 0);
  }
  const int col = nt * 16 + rc;
  const int row0 = mrow * 32 + wv * 16 + quad * 4;
  if constexpr (MODE == 1) {
    unsigned short* O2 = (unsigned short*)O2v;
    const float bb = bias[col];
#pragma unroll
    for (int r = 0; r < 4; ++r) {
      O1[(row0 + r) * 384 + col] = softplus_f(acc1[r] + bb);
      O2[(row0 + r) * 384 + col] = f2bf(acc2[r]);
    }
  } else {
    float* O2 = (float*)O2v;
#pragma unroll
    for (int r = 0; r < 4; ++r) {
      O1[(row0 + r) * 384 + col] = acc1[r];
      O2[(row0 + r) * 384 + col] = acc2[r];
    }
  }
}

// ---------------------------------------------------------------------------
// Conv + SiLU + transpose (unchanged from R7).
// ---------------------------------------------------------------------------
__global__ __launch_bounds__(256) void conv_tr_kernel(
    const float* __restrict__ x, const float* __restrict__ cw,
    const float* __restrict__ cb, const float* __restrict__ dt,
    float* __restrict__ u, float* __restrict__ dt_t,
    float* __restrict__ dtu_t) {
  __shared__ float Tdt[32][33];
  __shared__ float Tdu[32][33];
  const int tx = threadIdx.x;
  const int ty = threadIdx.y;
  const int b = blockIdx.z;
  const int i0 = blockIdx.y * 32;
  const int l0 = blockIdx.x * 32;
  const int gi = i0 + tx;
  const float cbv = cb[gi];
  const float cw0 = cw[gi * 4 + 0], cw1 = cw[gi * 4 + 1];
  const float cw2 = cw[gi * 4 + 2], cw3 = cw[gi * 4 + 3];
#pragma unroll
  for (int r = 0; r < 4; ++r) {
    const int l = l0 + ty + 8 * r;
    float acc = cbv;
    const float x3 = x[(b * L_SZ + l) * D_SZ + gi];
    const float x2 = (l >= 1) ? x[(b * L_SZ + l - 1) * D_SZ + gi] : 0.f;
    const float x1 = (l >= 2) ? x[(b * L_SZ + l - 2) * D_SZ + gi] : 0.f;
    const float x0 = (l >= 3) ? x[(b * L_SZ + l - 3) * D_SZ + gi] : 0.f;
    acc = fmaf(x0, cw0, acc);
    acc = fmaf(x1, cw1, acc);
    acc = fmaf(x2, cw2, acc);
    acc = fmaf(x3, cw3, acc);
    const float uv = acc / (1.f + __expf(-acc));
    const int off = (b * L_SZ + l) * D_SZ + gi;
    u[off] = uv;
    const float dtv = dt[off];
    Tdt[ty + 8 * r][tx] = dtv;
    Tdu[ty + 8 * r][tx] = dtv * uv;
  }
  __syncthreads();
#pragma unroll
  for (int r = 0; r < 4; ++r) {
    const int il = ty + 8 * r;
    const int off = (b * D_SZ + i0 + il) * L_SZ + l0 + tx;
    dt_t[off] = Tdt[tx][il];
    dtu_t[off] = Tdu[tx][il];
  }
}

// ---------------------------------------------------------------------------
// Selective scan v8: 3-way j-split (j = 128w + 2*lane + e), 2304 waves.
// HAND-PINNED pipeline: every chunk load is VOLATILE INLINE ASM (compiler
// cannot sink it — R4-R7 showed source-level fences fail, VGPR=40..52),
// with explicit `s_waitcnt vmcnt(24)` whose asm operands ("+v" on the chunk
// registers) create the dataflow so compute cannot be hoisted above the
// wait. 12 loads/chunk, 2 chunks always in flight (~24 outstanding).
// Chunk loads past l=383 read harmlessly into adjacent ws slots (counting
// stays uniform; results discarded). Value-fold butterfly (R5-verified);
// partials [w][b][i][l]; u*D in combine.
// ---------------------------------------------------------------------------
#define CH 8
struct Chunk {
  f32x4 d0, d1, u0, u1;
  f32x2 c0, c1, c2, c3, c4, c5, c6, c7;
};

#define STR2(x) #x
#define STR(x) STR2(x)

// dt/dtu: two dwordx4 each at imm offsets IA/IB (bytes). C: 8 dwordx2 rows,
// bases CB, CB+1152, CB+2304 floats with imm 0/1536/3072.
#define LOAD_CHUNK(K, CB, DTB, DUB, IA, IB)                                    \
  {                                                                            \
    asm volatile("global_load_dwordx4 %0, %1, off offset:" STR(IA)             \
                 : "=v"(K.d0) : "v"(DTB));                                     \
    asm volatile("global_load_dwordx4 %0, %1, off offset:" STR(IB)             \
                 : "=v"(K.d1) : "v"(DTB));                                     \
    asm volatile("global_load_dwordx4 %0, %1, off offset:" STR(IA)             \
                 : "=v"(K.u0) : "v"(DUB));                                     \
    asm volatile("global_load_dwordx4 %0, %1, off offset:" STR(IB)             \
                 : "=v"(K.u1) : "v"(DUB));                                     \
    const float* b1_ = (CB) + 1152;                                            \
    const float* b2_ = (CB) + 2304;                                            \
    asm volatile("global_load_dwordx2 %0, %1, off" : "=v"(K.c0) : "v"(CB));    \
    asm volatile("global_load_dwordx2 %0, %1, off offset:1536"                 \
                 : "=v"(K.c1) : "v"(CB));                                      \
    asm volatile("global_load_dwordx2 %0, %1, off offset:3072"                 \
                 : "=v"(K.c2) : "v"(CB));                                      \
    asm volatile("global_load_dwordx2 %0, %1, off" : "=v"(K.c3) : "v"(b1_));   \
    asm volatile("global_load_dwordx2 %0, %1, off offset:1536"                 \
                 : "=v"(K.c4) : "v"(b1_));                                     \
    asm volatile("global_load_dwordx2 %0, %1, off offset:3072"                 \
                 : "=v"(K.c5) : "v"(b1_));                                     \
    asm volatile("global_load_dwordx2 %0, %1, off" : "=v"(K.c6) : "v"(b2_));   \
    asm volatile("global_load_dwordx2 %0, %1, off offset:1536"                 \
                 : "=v"(K.c7) : "v"(b2_));                                     \
  }

#define WAIT_CHUNK(K)                                                          \
  asm volatile("s_waitcnt vmcnt(24)"                                           \
               : "+v"(K.d0), "+v"(K.d1), "+v"(K.u0), "+v"(K.u1), "+v"(K.c0),   \
                 "+v"(K.c1), "+v"(K.c2), "+v"(K.c3), "+v"(K.c4), "+v"(K.c5),   \
                 "+v"(K.c6), "+v"(K.c7))

__global__ __launch_bounds__(256, 3) void scan_kernel(
    const float* __restrict__ A_log, const float* __restrict__ dt_t,
    const float* __restrict__ dtu_t, const float* __restrict__ Bm,
    const float* __restrict__ Cm, float* __restrict__ part) {
  const int wid = ((blockIdx.x << 8) + (int)threadIdx.x) >> 6;  // 0..2303
  const int lane = threadIdx.x & 63;
  const int w = wid % 3;
  const int sid = wid / 3;
  const int b = sid / D_SZ;
  const int i = sid % D_SZ;
  const int j0 = w * 128 + 2 * lane;

  const float2 av = *(const float2*)(A_log + i * S_SZ + j0);
  const float2 bv = *(const float2*)(Bm + (b * D_SZ + i) * S_SZ + j0);
  float a20 = -__expf(av.x) * LOG2E;
  float a21 = -__expf(av.y) * LOG2E;
  float bw0 = bv.x, bw1 = bv.y;
  float h0 = 0.f, h1 = 0.f;

  const float* dtR = dt_t + (b * D_SZ + i) * L_SZ;
  const float* duR = dtu_t + (b * D_SZ + i) * L_SZ;
  const float* cC = Cm + b * BLK_ELEMS + j0;
  float* pp = part + ((w * B_SZ + b) * D_SZ + i) * L_SZ;

  const int sidx = ((lane & 1) << 2) | (lane & 2) | ((lane >> 2) & 1);
  const bool storer = lane < 8;

  // force compiler loads (a2*/bw*) to complete, then zero the vm counter so
  // LOAD_CHUNK/WAIT_CHUNK counting is exact.
  asm volatile("" :: "v"(a20), "v"(a21), "v"(bw0), "v"(bw1));
  asm volatile("s_waitcnt vmcnt(0)");

  float accs[8];
#define SSTEP(s, DT, DU, CC)                          \
  {                                                   \
    const float e0 = fexp2((DT)*a20);                 \
    const float e1 = fexp2((DT)*a21);                 \
    h0 = fmaf(e0, h0, bw0 * (DU));                    \
    h1 = fmaf(e1, h1, bw1 * (DU));                    \
    accs[s] = fmaf(h1, (CC)[1], h0 * (CC)[0]);        \
  }

  auto compute_chunk = [&](const Chunk& K, int l0) {
    SSTEP(0, K.d0[0], K.u0[0], K.c0);
    SSTEP(1, K.d0[1], K.u0[1], K.c1);
    SSTEP(2, K.d0[2], K.u0[2], K.c2);
    SSTEP(3, K.d0[3], K.u0[3], K.c3);
    SSTEP(4, K.d1[0], K.u1[0], K.c4);
    SSTEP(5, K.d1[1], K.u1[1], K.c5);
    SSTEP(6, K.d1[2], K.u1[2], K.c6);
    SSTEP(7, K.d1[3], K.u1[3], K.c7);
    {
      const bool s1 = (lane & 1) != 0;
#pragma unroll
      for (int q = 0; q < 4; ++q) {
        const float keep = s1 ? accs[q + 4] : accs[q];
        const float send = s1 ? accs[q] : accs[q + 4];
        accs[q] = keep + __shfl_xor(send, 1, 64);
      }
      const bool s2 = (lane & 2) != 0;
#pragma unroll
      for (int q = 0; q < 2; ++q) {
        const float keep = s2 ? accs[q + 2] : accs[q];
        const float send = s2 ? accs[q] : accs[q + 2];
        accs[q] = keep + __shfl_xor(send, 2, 64);
      }
      const bool s3 = (lane & 4) != 0;
      {
        const float keep = s3 ? accs[1] : accs[0];
        const float send = s3 ? accs[0] : accs[1];
        accs[0] = keep + __shfl_xor(send, 4, 64);
      }
    }
    float r = accs[0];
    r += __shfl_xor(r, 8, 64);
    r += __shfl_xor(r, 16, 64);
    r += __shfl_xor(r, 32, 64);
    if (storer) pp[l0 + sidx] = r;
  };

  Chunk K0, K1, K2;
  LOAD_CHUNK(K0, cC, dtR, duR, 0, 16);
  cC += 3072;
  LOAD_CHUNK(K1, cC, dtR, duR, 32, 48);
  cC += 3072;
  for (int it = 0; it < 16; ++it) {
    const int l0 = it * 24;
    LOAD_CHUNK(K2, cC, dtR, duR, 64, 80);
    cC += 3072;
    WAIT_CHUNK(K0);
    compute_chunk(K0, l0);
    LOAD_CHUNK(K0, cC, dtR, duR, 96, 112);
    cC += 3072;
    WAIT_CHUNK(K1);
    compute_chunk(K1, l0 + 8);
    LOAD_CHUNK(K1, cC, dtR, duR, 128, 144);
    cC += 3072;
    WAIT_CHUNK(K2);
    compute_chunk(K2, l0 + 16);
    dtR += 24;
    duR += 24;
  }
#undef SSTEP
}

// ---------------------------------------------------------------------------
// Combine + transpose: y[b,l,i] = sum_{w<3} part[w][b][i][l] + u[b,l,i]*D[i]
// ---------------------------------------------------------------------------
__global__ __launch_bounds__(256) void combine_kernel(
    const float* __restrict__ part, const float* __restrict__ u,
    const float* __restrict__ Dv, float* __restrict__ y) {
  __shared__ float T[32][33];
  const int tx = threadIdx.x;
  const int ty0 = threadIdx.y;
  const int b = blockIdx.z;
  const int i0 = blockIdx.y * 32;
  const int l0 = blockIdx.x * 32;
#pragma unroll
  for (int r = 0; r < 4; ++r) {
    const int il = ty0 + 8 * r;
    float s = 0.f;
#pragma unroll
    for (int w = 0; w < 3; ++w)
      s += part[((w * B_SZ + b) * D_SZ + i0 + il) * L_SZ + l0 + tx];
    T[il][tx] = s;
  }
  __syncthreads();
#pragma unroll
  for (int r = 0; r < 4; ++r) {
    const int ll = ty0 + 8 * r;
    const int gi = i0 + tx;
    const int off = (b * L_SZ + l0 + ll) * D_SZ + gi;
    y[off] = fmaf(u[off], Dv[gi], T[tx][ll]);
  }
}

extern "C" void kernel_launch(void* const* d_in, const int* in_sizes, int n_in,
                              void* d_out, int out_size, void* d_ws,
                              size_t ws_size, hipStream_t stream) {
  const float* x = (const float*)d_in[0];
  const float* A_log = (const float*)d_in[1];
  const float* D = (const float*)d_in[2];
  const float* dt_w = (const float*)d_in[3];
  const float* dt_b = (const float*)d_in[4];
  const float* B_w = (const float*)d_in[5];
  const float* C_w = (const float*)d_in[6];
  const float* conv_w = (const float*)d_in[7];
  const float* conv_b = (const float*)d_in[8];
  float* y = (float*)d_out;

  float* ws = (float*)d_ws;
  float* dt = ws;                     // slot 0  [b,l,i]
  float* u = ws + TOT_ELEMS;          // slot 1
  float* Bm = ws + 2 * TOT_ELEMS;     // slot 2
  float* Cm = ws + 3 * TOT_ELEMS;     // slot 3
  float* dt_t = ws + 4 * TOT_ELEMS;   // slot 4  [b,i,l]
  float* dtu_t = ws + 5 * TOT_ELEMS;  // slot 5  [b,i,l]
  float* part = ws + 6 * TOT_ELEMS;   // slots 6..8  [w][b][i][l] (w<3)
  unsigned short* bfarea = (unsigned short*)(ws + 10 * TOT_ELEMS);
  unsigned short* xbf = bfarea;                 // 294912
  unsigned short* dtwbf = bfarea + 294912;      // 147456
  unsigned short* Bwbf = bfarea + 442368;       // 147456
  unsigned short* Cwbf = bfarea + 589824;       // 147456
  unsigned short* xdblbf = bfarea + 737280;     // 294912

  cvt_bf16_kernel<<<720, 256, 0, stream>>>(x, dt_w, B_w, C_w, xbf, dtwbf, Bwbf, Cwbf);
  mfma_dual_gemm<1><<<dim3(24, 24), 128, 0, stream>>>(xbf, dtwbf, Bwbf, dt_b, dt, xdblbf);
  mfma_dual_gemm<2><<<dim3(24, 24), 128, 0, stream>>>(xdblbf, Bwbf, Cwbf, nullptr, Bm, Cm);
  conv_tr_kernel<<<dim3(L_SZ / 32, D_SZ / 32, B_SZ), dim3(32, 8), 0, stream>>>(
      x, conv_w, conv_b, dt, u, dt_t, dtu_t);
  scan_kernel<<<576, 256, 0, stream>>>(A_log, dt_t, dtu_t, Bm, Cm, part);
  combine_kernel<<<dim3(L_SZ / 32, D_SZ / 32, B_SZ), dim3(32, 8), 0, stream>>>(
      part, u, D, y);
}

// Round 10
// 143.433 us; speedup vs baseline: 1.1452x; 1.0376x over previous
//
#include <hip/hip_runtime.h>
#include <math.h>

// Dims (fixed by the problem)
#define B_SZ 2
#define L_SZ 384
#define D_SZ 384
#define S_SZ 384
#define BLK_ELEMS (L_SZ * D_SZ)        // 147456 per batch
#define TOT_ELEMS (B_SZ * L_SZ * D_SZ) // 294912
#define LOG2E 1.4426950408889634f

typedef __attribute__((ext_vector_type(8))) short bf16x8;
typedef __attribute__((ext_vector_type(4))) float f32x4;

__device__ __forceinline__ float fexp2(float x) {
  return __builtin_amdgcn_exp2f(x);
}
__device__ __forceinline__ float softplus_f(float z) {
  return (z > 20.f) ? z : log1pf(__expf(z));
}
__device__ __forceinline__ unsigned short f2bf(float f) {  // RNE f32->bf16
  unsigned int u = __float_as_uint(f);
  return (unsigned short)((u + 0x7FFFu + ((u >> 16) & 1u)) >> 16);
}
#define PIPELINE_FENCE() asm volatile("" ::: "memory")

// ---------------------------------------------------------------------------
// Convert x, dt_w, B_w, C_w to bf16.
// ---------------------------------------------------------------------------
__global__ __launch_bounds__(256) void cvt_bf16_kernel(
    const float* __restrict__ x, const float* __restrict__ dt_w,
    const float* __restrict__ B_w, const float* __restrict__ C_w,
    unsigned short* __restrict__ xbf, unsigned short* __restrict__ dtwbf,
    unsigned short* __restrict__ Bwbf, unsigned short* __restrict__ Cwbf) {
  const int blk = blockIdx.x;
  const float* src;
  unsigned short* dst;
  int base;
  if (blk < 288) { src = x; dst = xbf; base = blk; }
  else if (blk < 432) { src = dt_w; dst = dtwbf; base = blk - 288; }
  else if (blk < 576) { src = B_w; dst = Bwbf; base = blk - 432; }
  else { src = C_w; dst = Cwbf; base = blk - 576; }
  const int idx = base * 1024 + threadIdx.x * 4;
  const float4 v = *(const float4*)(src + idx);
  ushort4 o;
  o.x = f2bf(v.x); o.y = f2bf(v.y); o.z = f2bf(v.z); o.w = f2bf(v.w);
  *(ushort4*)(dst + idx) = o;
}

// ---------------------------------------------------------------------------
// LDS-staged dual MFMA NT-GEMM (unchanged from R9 — isolate scan change;
// GEMM counters will surface in next round's top-5 once scan < GEMM).
// ---------------------------------------------------------------------------
template <int MODE>
__global__ __launch_bounds__(128, 2) void mfma_dual_gemm(
    const unsigned short* __restrict__ Abf,
    const unsigned short* __restrict__ W1bf,
    const unsigned short* __restrict__ W2bf,
    const float* __restrict__ bias,
    float* __restrict__ O1, void* __restrict__ O2v) {
  __shared__ unsigned short sA[32 * 392];
  __shared__ unsigned short sW1[16 * 392];
  __shared__ unsigned short sW2[16 * 392];

  const int t = threadIdx.x;
  const int wv = t >> 6;
  const int lane = t & 63;
  const int nt = blockIdx.x;
  const int mrow = blockIdx.y;

  const unsigned short* Ab = Abf + mrow * 32 * 384;
  const unsigned short* W1b = W1bf + nt * 16 * 384;
  const unsigned short* W2b = W2bf + nt * 16 * 384;

#pragma unroll
  for (int it = 0; it < 12; ++it) {
    const int id = t + it * 128;
    const int row = id / 48, col = id - row * 48;
    *(bf16x8*)&sA[row * 392 + col * 8] = *(const bf16x8*)(Ab + id * 8);
  }
#pragma unroll
  for (int it = 0; it < 6; ++it) {
    const int id = t + it * 128;
    const int row = id / 48, col = id - row * 48;
    *(bf16x8*)&sW1[row * 392 + col * 8] = *(const bf16x8*)(W1b + id * 8);
    *(bf16x8*)&sW2[row * 392 + col * 8] = *(const bf16x8*)(W2b + id * 8);
  }
  __syncthreads();

  const int rc = lane & 15;
  const int quad = lane >> 4;
  bf16x8 af[12], w1f[12], w2f[12];
#pragma unroll
  for (int kt = 0; kt < 12; ++kt) {
    af[kt] = *(const bf16x8*)&sA[(wv * 16 + rc) * 392 + quad * 8 + kt * 32];
    w1f[kt] = *(const bf16x8*)&sW1[rc * 392 + quad * 8 + kt * 32];
    w2f[kt] = *(const bf16x8*)&sW2[rc * 392 + quad * 8 + kt * 32];
  }
  PIPELINE_FENCE();
  f32x4 acc1 = {0.f, 0.f, 0.f, 0.f};
  f32x4 acc2 = {0.f, 0.f, 0.f, 0.f};
#pragma unroll
  for (int kt = 0; kt < 12; ++kt) {
    acc1 = __builtin_amdgcn_mfma_f32_16x16x32_bf16(af[kt], w1f[kt], acc1, 0, 0, 0);
    acc2 = __builtin_amdgcn_mfma_f32_16x16x32_bf16(af[kt], w2f[kt], acc2, 0, 0, 0);
  }
  const int col = nt * 16 + rc;
  const int row0 = mrow * 32 + wv * 16 + quad * 4;
  if constexpr (MODE == 1) {
    unsigned short* O2 = (unsigned short*)O2v;
    const float bb = bias[col];
#pragma unroll
    for (int r = 0; r < 4; ++r) {
      O1[(row0 + r) * 384 + col] = softplus_f(acc1[r] + bb);
      O2[(row0 + r) * 384 + col] = f2bf(acc2[r]);
    }
  } else {
    float* O2 = (float*)O2v;
#pragma unroll
    for (int r = 0; r < 4; ++r) {
      O1[(row0 + r) * 384 + col] = acc1[r];
      O2[(row0 + r) * 384 + col] = acc2[r];
    }
  }
}

// ---------------------------------------------------------------------------
// Conv + SiLU + transpose (unchanged).
// ---------------------------------------------------------------------------
__global__ __launch_bounds__(256) void conv_tr_kernel(
    const float* __restrict__ x, const float* __restrict__ cw,
    const float* __restrict__ cb, const float* __restrict__ dt,
    float* __restrict__ u, float* __restrict__ dt_t,
    float* __restrict__ dtu_t) {
  __shared__ float Tdt[32][33];
  __shared__ float Tdu[32][33];
  const int tx = threadIdx.x;
  const int ty = threadIdx.y;
  const int b = blockIdx.z;
  const int i0 = blockIdx.y * 32;
  const int l0 = blockIdx.x * 32;
  const int gi = i0 + tx;
  const float cbv = cb[gi];
  const float cw0 = cw[gi * 4 + 0], cw1 = cw[gi * 4 + 1];
  const float cw2 = cw[gi * 4 + 2], cw3 = cw[gi * 4 + 3];
#pragma unroll
  for (int r = 0; r < 4; ++r) {
    const int l = l0 + ty + 8 * r;
    float acc = cbv;
    const float x3 = x[(b * L_SZ + l) * D_SZ + gi];
    const float x2 = (l >= 1) ? x[(b * L_SZ + l - 1) * D_SZ + gi] : 0.f;
    const float x1 = (l >= 2) ? x[(b * L_SZ + l - 2) * D_SZ + gi] : 0.f;
    const float x0 = (l >= 3) ? x[(b * L_SZ + l - 3) * D_SZ + gi] : 0.f;
    acc = fmaf(x0, cw0, acc);
    acc = fmaf(x1, cw1, acc);
    acc = fmaf(x2, cw2, acc);
    acc = fmaf(x3, cw3, acc);
    const float uv = acc / (1.f + __expf(-acc));
    const int off = (b * L_SZ + l) * D_SZ + gi;
    u[off] = uv;
    const float dtv = dt[off];
    Tdt[ty + 8 * r][tx] = dtv;
    Tdu[ty + 8 * r][tx] = dtv * uv;
  }
  __syncthreads();
#pragma unroll
  for (int r = 0; r < 4; ++r) {
    const int il = ty + 8 * r;
    const int off = (b * D_SZ + i0 + il) * L_SZ + l0 + tx;
    dt_t[off] = Tdt[tx][il];
    dtu_t[off] = Tdu[tx][il];
  }
}

// ---------------------------------------------------------------------------
// Selective scan v9: Tc=2 channels per wave x 6-way j-split (1 state/lane,
// j = 64w + lane). 2304 waves in 768 blocks x 3 waves = exactly 3 blocks/CU.
// R9 diagnosis: TA line-throughput bound (12 VMEM instrs/chunk, 128 line
// splits). v9 per 16-step chunk: 16 Cm loads (4 lines each, shared by BOTH
// channels) + ONE combo load where the 64 lanes fetch all 64 dt/dtu scalars
// (extracted with v_readlane -> zero further memory traffic). Loads are
// volatile asm with explicit vmcnt(34) waits (2-chunk latency cover).
// Fold: 32 accs -> bitrev5 lane mapping, 5 select+shfl stages + xor32.
// ---------------------------------------------------------------------------
struct ChunkV {
  float combo;
  float c[16];
};

#define LOAD_CHUNK(K, B0, B1, B2, B3, B4, B5, CMB)                             \
  {                                                                            \
    asm volatile("global_load_dword %0, %1, off" : "=v"(K.combo) : "v"(CMB));  \
    asm volatile("global_load_dword %0, %1, off" : "=v"(K.c[0]) : "v"(B0));    \
    asm volatile("global_load_dword %0, %1, off offset:1536"                   \
                 : "=v"(K.c[1]) : "v"(B0));                                    \
    asm volatile("global_load_dword %0, %1, off offset:3072"                   \
                 : "=v"(K.c[2]) : "v"(B0));                                    \
    asm volatile("global_load_dword %0, %1, off" : "=v"(K.c[3]) : "v"(B1));    \
    asm volatile("global_load_dword %0, %1, off offset:1536"                   \
                 : "=v"(K.c[4]) : "v"(B1));                                    \
    asm volatile("global_load_dword %0, %1, off offset:3072"                   \
                 : "=v"(K.c[5]) : "v"(B1));                                    \
    asm volatile("global_load_dword %0, %1, off" : "=v"(K.c[6]) : "v"(B2));    \
    asm volatile("global_load_dword %0, %1, off offset:1536"                   \
                 : "=v"(K.c[7]) : "v"(B2));                                    \
    asm volatile("global_load_dword %0, %1, off offset:3072"                   \
                 : "=v"(K.c[8]) : "v"(B2));                                    \
    asm volatile("global_load_dword %0, %1, off" : "=v"(K.c[9]) : "v"(B3));    \
    asm volatile("global_load_dword %0, %1, off offset:1536"                   \
                 : "=v"(K.c[10]) : "v"(B3));                                   \
    asm volatile("global_load_dword %0, %1, off offset:3072"                   \
                 : "=v"(K.c[11]) : "v"(B3));                                   \
    asm volatile("global_load_dword %0, %1, off" : "=v"(K.c[12]) : "v"(B4));   \
    asm volatile("global_load_dword %0, %1, off offset:1536"                   \
                 : "=v"(K.c[13]) : "v"(B4));                                   \
    asm volatile("global_load_dword %0, %1, off offset:3072"                   \
                 : "=v"(K.c[14]) : "v"(B4));                                   \
    asm volatile("global_load_dword %0, %1, off" : "=v"(K.c[15]) : "v"(B5));   \
  }

#define WAIT_CHUNK(K)                                                          \
  asm volatile("s_waitcnt vmcnt(34)"                                           \
               : "+v"(K.combo), "+v"(K.c[0]), "+v"(K.c[1]), "+v"(K.c[2]),      \
                 "+v"(K.c[3]), "+v"(K.c[4]), "+v"(K.c[5]), "+v"(K.c[6]),       \
                 "+v"(K.c[7]), "+v"(K.c[8]), "+v"(K.c[9]), "+v"(K.c[10]),      \
                 "+v"(K.c[11]), "+v"(K.c[12]), "+v"(K.c[13]), "+v"(K.c[14]),   \
                 "+v"(K.c[15]))

#define ADV_BASES()                                                            \
  {                                                                            \
    cb0 += 6144; cb1 += 6144; cb2 += 6144;                                     \
    cb3 += 6144; cb4 += 6144; cb5 += 6144; cmb += 16;                          \
  }

__global__ __launch_bounds__(192, 3) void scan_kernel(
    const float* __restrict__ A_log, const float* __restrict__ dt_t,
    const float* __restrict__ dtu_t, const float* __restrict__ Bm,
    const float* __restrict__ Cm, float* __restrict__ part) {
  const int wave = blockIdx.x * 3 + (threadIdx.x >> 6);  // 0..2303
  const int lane = threadIdx.x & 63;
  const int w = wave % 6;            // j-split
  const int grp = wave / 6;          // 0..383
  const int b = grp / 192;
  const int i0 = (grp % 192) * 2;    // channels i0, i0+1
  const int j = w * 64 + lane;

  const float al0 = A_log[(i0 + 0) * S_SZ + j];
  const float al1 = A_log[(i0 + 1) * S_SZ + j];
  const float bw0 = Bm[(b * D_SZ + i0 + 0) * S_SZ + j];
  const float bw1 = Bm[(b * D_SZ + i0 + 1) * S_SZ + j];
  const float a20 = -__expf(al0) * LOG2E;
  const float a21 = -__expf(al1) * LOG2E;
  float h0 = 0.f, h1 = 0.f;

  // combo base: lane -> (var, ch, s): var=lane>>5 (0=dt,1=dtu),
  // ch=(lane>>4)&1, s=lane&15
  const int var = lane >> 5;
  const int cch = (lane >> 4) & 1;
  const int cs = lane & 15;
  const float* cmb =
      (var ? dtu_t : dt_t) + (b * D_SZ + i0 + cch) * L_SZ + cs;

  // Cm bases: per-lane rows 0,3,6,9,12,15 (offsets 0/1536/3072 cover 16 rows)
  const float* cmrow = Cm + b * BLK_ELEMS + j;
  const float* cb0 = cmrow;
  const float* cb1 = cmrow + 3 * D_SZ;
  const float* cb2 = cmrow + 6 * D_SZ;
  const float* cb3 = cmrow + 9 * D_SZ;
  const float* cb4 = cmrow + 12 * D_SZ;
  const float* cb5 = cmrow + 15 * D_SZ;

  // store mapping: lane<32 stores reduction k=bitrev5(lane): ch=k>>4, s=k&15
  const int k = ((lane & 1) << 4) | ((lane & 2) << 2) | (lane & 4) |
                ((lane & 8) >> 2) | ((lane & 16) >> 4);
  float* pstore =
      part + ((w * B_SZ + b) * D_SZ + i0) * L_SZ + (k >> 4) * L_SZ + (k & 15);
  const bool storer = lane < 32;

  // drain initial compiler loads so vmcnt counting is exact
  asm volatile("" :: "v"(a20), "v"(a21), "v"(bw0), "v"(bw1));
  asm volatile("s_waitcnt vmcnt(0)");

  auto compute_chunk = [&](ChunkV& K) {
    float acc[32];
    const int combo_i = __float_as_int(K.combo);
#pragma unroll
    for (int s = 0; s < 16; ++s) {
      const float dt0 = __int_as_float(__builtin_amdgcn_readlane(combo_i, s));
      const float dt1 =
          __int_as_float(__builtin_amdgcn_readlane(combo_i, 16 + s));
      const float du0 =
          __int_as_float(__builtin_amdgcn_readlane(combo_i, 32 + s));
      const float du1 =
          __int_as_float(__builtin_amdgcn_readlane(combo_i, 48 + s));
      const float e0 = fexp2(dt0 * a20);
      const float e1 = fexp2(dt1 * a21);
      h0 = fmaf(e0, h0, bw0 * du0);
      h1 = fmaf(e1, h1, bw1 * du1);
      acc[s] = h0 * K.c[s];
      acc[16 + s] = h1 * K.c[s];
    }
    // value-fold: 5 stages (d=1,2,4,8,16), then complete across halves
#pragma unroll
    for (int st = 0; st < 5; ++st) {
      const int d = 1 << st;
      const int n2 = 16 >> st;  // half-count at this stage
      const bool hi = (lane & d) != 0;
#pragma unroll
      for (int q = 0; q < 16; ++q) {
        if (q < n2) {
          const float keep = hi ? acc[q + n2] : acc[q];
          const float send = hi ? acc[q] : acc[q + n2];
          acc[q] = keep + __shfl_xor(send, d, 64);
        }
      }
    }
    float r = acc[0];
    r += __shfl_xor(r, 32, 64);
    if (storer) *pstore = r;
    pstore += 16;
  };

  ChunkV K0, K1, K2;
  LOAD_CHUNK(K0, cb0, cb1, cb2, cb3, cb4, cb5, cmb);
  ADV_BASES();
  LOAD_CHUNK(K1, cb0, cb1, cb2, cb3, cb4, cb5, cmb);
  ADV_BASES();
#pragma unroll 1
  for (int mit = 0; mit < 8; ++mit) {
    LOAD_CHUNK(K2, cb0, cb1, cb2, cb3, cb4, cb5, cmb);
    ADV_BASES();
    WAIT_CHUNK(K0);
    compute_chunk(K0);
    LOAD_CHUNK(K0, cb0, cb1, cb2, cb3, cb4, cb5, cmb);
    ADV_BASES();
    WAIT_CHUNK(K1);
    compute_chunk(K1);
    LOAD_CHUNK(K1, cb0, cb1, cb2, cb3, cb4, cb5, cmb);
    ADV_BASES();
    WAIT_CHUNK(K2);
    compute_chunk(K2);
  }
}

// ---------------------------------------------------------------------------
// Combine + transpose: y[b,l,i] = sum_{w<6} part[w][b][i][l] + u[b,l,i]*D[i]
// ---------------------------------------------------------------------------
__global__ __launch_bounds__(256) void combine_kernel(
    const float* __restrict__ part, const float* __restrict__ u,
    const float* __restrict__ Dv, float* __restrict__ y) {
  __shared__ float T[32][33];
  const int tx = threadIdx.x;
  const int ty0 = threadIdx.y;
  const int b = blockIdx.z;
  const int i0 = blockIdx.y * 32;
  const int l0 = blockIdx.x * 32;
#pragma unroll
  for (int r = 0; r < 4; ++r) {
    const int il = ty0 + 8 * r;
    float s = 0.f;
#pragma unroll
    for (int w = 0; w < 6; ++w)
      s += part[((w * B_SZ + b) * D_SZ + i0 + il) * L_SZ + l0 + tx];
    T[il][tx] = s;
  }
  __syncthreads();
#pragma unroll
  for (int r = 0; r < 4; ++r) {
    const int ll = ty0 + 8 * r;
    const int gi = i0 + tx;
    const int off = (b * L_SZ + l0 + ll) * D_SZ + gi;
    y[off] = fmaf(u[off], Dv[gi], T[tx][ll]);
  }
}

extern "C" void kernel_launch(void* const* d_in, const int* in_sizes, int n_in,
                              void* d_out, int out_size, void* d_ws,
                              size_t ws_size, hipStream_t stream) {
  const float* x = (const float*)d_in[0];
  const float* A_log = (const float*)d_in[1];
  const float* D = (const float*)d_in[2];
  const float* dt_w = (const float*)d_in[3];
  const float* dt_b = (const float*)d_in[4];
  const float* B_w = (const float*)d_in[5];
  const float* C_w = (const float*)d_in[6];
  const float* conv_w = (const float*)d_in[7];
  const float* conv_b = (const float*)d_in[8];
  float* y = (float*)d_out;

  float* ws = (float*)d_ws;
  float* dt = ws;                     // slot 0  [b,l,i]
  float* u = ws + TOT_ELEMS;          // slot 1
  float* Bm = ws + 2 * TOT_ELEMS;     // slot 2
  float* Cm = ws + 3 * TOT_ELEMS;     // slot 3
  float* dt_t = ws + 4 * TOT_ELEMS;   // slot 4  [b,i,l]
  float* dtu_t = ws + 5 * TOT_ELEMS;  // slot 5  [b,i,l]
  float* part = ws + 6 * TOT_ELEMS;   // slots 6..11  [w][b][i][l], w<6
  unsigned short* bfarea = (unsigned short*)(ws + 12 * TOT_ELEMS);
  unsigned short* xbf = bfarea;                 // 294912
  unsigned short* dtwbf = bfarea + 294912;      // 147456
  unsigned short* Bwbf = bfarea + 442368;       // 147456
  unsigned short* Cwbf = bfarea + 589824;       // 147456
  unsigned short* xdblbf = bfarea + 737280;     // 294912

  cvt_bf16_kernel<<<720, 256, 0, stream>>>(x, dt_w, B_w, C_w, xbf, dtwbf, Bwbf, Cwbf);
  mfma_dual_gemm<1><<<dim3(24, 24), 128, 0, stream>>>(xbf, dtwbf, Bwbf, dt_b, dt, xdblbf);
  mfma_dual_gemm<2><<<dim3(24, 24), 128, 0, stream>>>(xdblbf, Bwbf, Cwbf, nullptr, Bm, Cm);
  conv_tr_kernel<<<dim3(L_SZ / 32, D_SZ / 32, B_SZ), dim3(32, 8), 0, stream>>>(
      x, conv_w, conv_b, dt, u, dt_t, dtu_t);
  scan_kernel<<<768, 192, 0, stream>>>(A_log, dt_t, dtu_t, Bm, Cm, part);
  combine_kernel<<<dim3(L_SZ / 32, D_SZ / 32, B_SZ), dim3(32, 8), 0, stream>>>(
      part, u, D, y);
}

// Round 11
// 138.929 us; speedup vs baseline: 1.1824x; 1.0324x over previous
//
#include <hip/hip_runtime.h>
#include <math.h>

// Dims (fixed by the problem)
#define B_SZ 2
#define L_SZ 384
#define D_SZ 384
#define S_SZ 384
#define BLK_ELEMS (L_SZ * D_SZ)        // 147456 per batch
#define TOT_ELEMS (B_SZ * L_SZ * D_SZ) // 294912
#define LOG2E 1.4426950408889634f

typedef __attribute__((ext_vector_type(8))) short bf16x8;
typedef __attribute__((ext_vector_type(4))) float f32x4;

__device__ __forceinline__ float fexp2(float x) {
  return __builtin_amdgcn_exp2f(x);
}
__device__ __forceinline__ float softplus_f(float z) {
  return (z > 20.f) ? z : log1pf(__expf(z));
}
__device__ __forceinline__ unsigned short f2bf(float f) {  // RNE f32->bf16
  unsigned int u = __float_as_uint(f);
  return (unsigned short)((u + 0x7FFFu + ((u >> 16) & 1u)) >> 16);
}
#define PIPELINE_FENCE() asm volatile("" ::: "memory")

// DPP lane exchange (VALU pipe — no DS latency). CTRL: 0x140=row_mirror
// (xor15), 0x141=row_half_mirror (xor7), 0xB1=quad_perm[1,0,3,2] (xor1).
template <int CTRL>
__device__ __forceinline__ float dpp_mov(float v) {
  return __int_as_float(
      __builtin_amdgcn_update_dpp(0, __float_as_int(v), CTRL, 0xF, 0xF, true));
}

// ---------------------------------------------------------------------------
// Convert x, dt_w, B_w, C_w to bf16.
// ---------------------------------------------------------------------------
__global__ __launch_bounds__(256) void cvt_bf16_kernel(
    const float* __restrict__ x, const float* __restrict__ dt_w,
    const float* __restrict__ B_w, const float* __restrict__ C_w,
    unsigned short* __restrict__ xbf, unsigned short* __restrict__ dtwbf,
    unsigned short* __restrict__ Bwbf, unsigned short* __restrict__ Cwbf) {
  const int blk = blockIdx.x;
  const float* src;
  unsigned short* dst;
  int base;
  if (blk < 288) { src = x; dst = xbf; base = blk; }
  else if (blk < 432) { src = dt_w; dst = dtwbf; base = blk - 288; }
  else if (blk < 576) { src = B_w; dst = Bwbf; base = blk - 432; }
  else { src = C_w; dst = Cwbf; base = blk - 576; }
  const int idx = base * 1024 + threadIdx.x * 4;
  const float4 v = *(const float4*)(src + idx);
  ushort4 o;
  o.x = f2bf(v.x); o.y = f2bf(v.y); o.z = f2bf(v.z); o.w = f2bf(v.w);
  *(ushort4*)(dst + idx) = o;
}

// ---------------------------------------------------------------------------
// LDS-staged dual MFMA NT-GEMM (unchanged from R9/R10).
// ---------------------------------------------------------------------------
template <int MODE>
__global__ __launch_bounds__(128, 2) void mfma_dual_gemm(
    const unsigned short* __restrict__ Abf,
    const unsigned short* __restrict__ W1bf,
    const unsigned short* __restrict__ W2bf,
    const float* __restrict__ bias,
    float* __restrict__ O1, void* __restrict__ O2v) {
  __shared__ unsigned short sA[32 * 392];
  __shared__ unsigned short sW1[16 * 392];
  __shared__ unsigned short sW2[16 * 392];

  const int t = threadIdx.x;
  const int wv = t >> 6;
  const int lane = t & 63;
  const int nt = blockIdx.x;
  const int mrow = blockIdx.y;

  const unsigned short* Ab = Abf + mrow * 32 * 384;
  const unsigned short* W1b = W1bf + nt * 16 * 384;
  const unsigned short* W2b = W2bf + nt * 16 * 384;

#pragma unroll
  for (int it = 0; it < 12; ++it) {
    const int id = t + it * 128;
    const int row = id / 48, col = id - row * 48;
    *(bf16x8*)&sA[row * 392 + col * 8] = *(const bf16x8*)(Ab + id * 8);
  }
#pragma unroll
  for (int it = 0; it < 6; ++it) {
    const int id = t + it * 128;
    const int row = id / 48, col = id - row * 48;
    *(bf16x8*)&sW1[row * 392 + col * 8] = *(const bf16x8*)(W1b + id * 8);
    *(bf16x8*)&sW2[row * 392 + col * 8] = *(const bf16x8*)(W2b + id * 8);
  }
  __syncthreads();

  const int rc = lane & 15;
  const int quad = lane >> 4;
  bf16x8 af[12], w1f[12], w2f[12];
#pragma unroll
  for (int kt = 0; kt < 12; ++kt) {
    af[kt] = *(const bf16x8*)&sA[(wv * 16 + rc) * 392 + quad * 8 + kt * 32];
    w1f[kt] = *(const bf16x8*)&sW1[rc * 392 + quad * 8 + kt * 32];
    w2f[kt] = *(const bf16x8*)&sW2[rc * 392 + quad * 8 + kt * 32];
  }
  PIPELINE_FENCE();
  f32x4 acc1 = {0.f, 0.f, 0.f, 0.f};
  f32x4 acc2 = {0.f, 0.f, 0.f, 0.f};
#pragma unroll
  for (int kt = 0; kt < 12; ++kt) {
    acc1 = __builtin_amdgcn_mfma_f32_16x16x32_bf16(af[kt], w1f[kt], acc1, 0, 0, 0);
    acc2 = __builtin_amdgcn_mfma_f32_16x16x32_bf16(af[kt], w2f[kt], acc2, 0, 0, 0);
  }
  const int col = nt * 16 + rc;
  const int row0 = mrow * 32 + wv * 16 + quad * 4;
  if constexpr (MODE == 1) {
    unsigned short* O2 = (unsigned short*)O2v;
    const float bb = bias[col];
#pragma unroll
    for (int r = 0; r < 4; ++r) {
      O1[(row0 + r) * 384 + col] = softplus_f(acc1[r] + bb);
      O2[(row0 + r) * 384 + col] = f2bf(acc2[r]);
    }
  } else {
    float* O2 = (float*)O2v;
#pragma unroll
    for (int r = 0; r < 4; ++r) {
      O1[(row0 + r) * 384 + col] = acc1[r];
      O2[(row0 + r) * 384 + col] = acc2[r];
    }
  }
}

// ---------------------------------------------------------------------------
// Conv + SiLU + transpose (unchanged).
// ---------------------------------------------------------------------------
__global__ __launch_bounds__(256) void conv_tr_kernel(
    const float* __restrict__ x, const float* __restrict__ cw,
    const float* __restrict__ cb, const float* __restrict__ dt,
    float* __restrict__ u, float* __restrict__ dt_t,
    float* __restrict__ dtu_t) {
  __shared__ float Tdt[32][33];
  __shared__ float Tdu[32][33];
  const int tx = threadIdx.x;
  const int ty = threadIdx.y;
  const int b = blockIdx.z;
  const int i0 = blockIdx.y * 32;
  const int l0 = blockIdx.x * 32;
  const int gi = i0 + tx;
  const float cbv = cb[gi];
  const float cw0 = cw[gi * 4 + 0], cw1 = cw[gi * 4 + 1];
  const float cw2 = cw[gi * 4 + 2], cw3 = cw[gi * 4 + 3];
#pragma unroll
  for (int r = 0; r < 4; ++r) {
    const int l = l0 + ty + 8 * r;
    float acc = cbv;
    const float x3 = x[(b * L_SZ + l) * D_SZ + gi];
    const float x2 = (l >= 1) ? x[(b * L_SZ + l - 1) * D_SZ + gi] : 0.f;
    const float x1 = (l >= 2) ? x[(b * L_SZ + l - 2) * D_SZ + gi] : 0.f;
    const float x0 = (l >= 3) ? x[(b * L_SZ + l - 3) * D_SZ + gi] : 0.f;
    acc = fmaf(x0, cw0, acc);
    acc = fmaf(x1, cw1, acc);
    acc = fmaf(x2, cw2, acc);
    acc = fmaf(x3, cw3, acc);
    const float uv = acc / (1.f + __expf(-acc));
    const int off = (b * L_SZ + l) * D_SZ + gi;
    u[off] = uv;
    const float dtv = dt[off];
    Tdt[ty + 8 * r][tx] = dtv;
    Tdu[ty + 8 * r][tx] = dtv * uv;
  }
  __syncthreads();
#pragma unroll
  for (int r = 0; r < 4; ++r) {
    const int il = ty + 8 * r;
    const int off = (b * D_SZ + i0 + il) * L_SZ + l0 + tx;
    dt_t[off] = Tdt[tx][il];
    dtu_t[off] = Tdu[tx][il];
  }
}

// ---------------------------------------------------------------------------
// Selective scan v11: Tc=1, 6-way j-split (j = 64w + lane), 4608 waves
// (4.5 waves/SIMD — R10's Tc=2 halved TLP for the same issue cost).
// Per 8-step chunk: 8 per-lane Cm dword loads (coalesced 256B rows) +
// 4 wave-uniform dwordx4 loads of dt/dtu (1 line each; R10's readlane
// extraction cost 128 issue-cyc/chunk — removed). Loads volatile-asm
// pinned, vmcnt(24) = 2-chunk latency cover. Value-fold via DPP pairings
// xor15(row_mirror)/xor7(row_half_mirror)/xor1(quad_perm) — VALU pipe —
// then 3 plain shfl_xor butterflies (2/16/32): DS ops 32 -> 3 per chunk.
// ---------------------------------------------------------------------------
struct ChunkS {
  f32x4 d0, d1, u0, u1;
  float c[8];
};

#define LOAD_CHUNK(K, B0, B1, B2, DTB, DUB)                                    \
  {                                                                            \
    asm volatile("global_load_dwordx4 %0, %1, off" : "=v"(K.d0) : "v"(DTB));   \
    asm volatile("global_load_dwordx4 %0, %1, off offset:16"                   \
                 : "=v"(K.d1) : "v"(DTB));                                     \
    asm volatile("global_load_dwordx4 %0, %1, off" : "=v"(K.u0) : "v"(DUB));   \
    asm volatile("global_load_dwordx4 %0, %1, off offset:16"                   \
                 : "=v"(K.u1) : "v"(DUB));                                     \
    asm volatile("global_load_dword %0, %1, off" : "=v"(K.c[0]) : "v"(B0));    \
    asm volatile("global_load_dword %0, %1, off offset:1536"                   \
                 : "=v"(K.c[1]) : "v"(B0));                                    \
    asm volatile("global_load_dword %0, %1, off offset:3072"                   \
                 : "=v"(K.c[2]) : "v"(B0));                                    \
    asm volatile("global_load_dword %0, %1, off" : "=v"(K.c[3]) : "v"(B1));    \
    asm volatile("global_load_dword %0, %1, off offset:1536"                   \
                 : "=v"(K.c[4]) : "v"(B1));                                    \
    asm volatile("global_load_dword %0, %1, off offset:3072"                   \
                 : "=v"(K.c[5]) : "v"(B1));                                    \
    asm volatile("global_load_dword %0, %1, off" : "=v"(K.c[6]) : "v"(B2));    \
    asm volatile("global_load_dword %0, %1, off offset:1536"                   \
                 : "=v"(K.c[7]) : "v"(B2));                                    \
  }

#define WAIT_CHUNK(K)                                                          \
  asm volatile("s_waitcnt vmcnt(24)"                                           \
               : "+v"(K.d0), "+v"(K.d1), "+v"(K.u0), "+v"(K.u1),               \
                 "+v"(K.c[0]), "+v"(K.c[1]), "+v"(K.c[2]), "+v"(K.c[3]),       \
                 "+v"(K.c[4]), "+v"(K.c[5]), "+v"(K.c[6]), "+v"(K.c[7]))

#define ADV_BASES()                                                            \
  { cb0 += 3072; cb1 += 3072; cb2 += 3072; dtB += 8; duB += 8; }

__global__ __launch_bounds__(64, 4) void scan_kernel(
    const float* __restrict__ A_log, const float* __restrict__ dt_t,
    const float* __restrict__ dtu_t, const float* __restrict__ Bm,
    const float* __restrict__ Cm, float* __restrict__ part) {
  const int wave = blockIdx.x;       // 0..4607
  const int lane = threadIdx.x;      // 0..63
  const int w = wave % 6;            // j-split
  const int sid = wave / 6;          // 0..767
  const int b = sid / D_SZ;
  const int i = sid % D_SZ;
  const int j = w * 64 + lane;

  const float a2 = -__expf(A_log[i * S_SZ + j]) * LOG2E;
  const float bw = Bm[(b * D_SZ + i) * S_SZ + j];
  float h = 0.f;

  const float* dtB = dt_t + (b * D_SZ + i) * L_SZ;   // uniform, contiguous l
  const float* duB = dtu_t + (b * D_SZ + i) * L_SZ;
  // Cm row bases (rows 0..2, 3..5, 6..7 of each chunk via imm 0/1536/3072)
  const float* cmrow = Cm + b * BLK_ELEMS + j;
  const float* cb0 = cmrow;
  const float* cb1 = cmrow + 3 * D_SZ;
  const float* cb2 = cmrow + 6 * D_SZ;

  // fold result mapping: lane r holds value s = (b3<<2)|(b2<<1)|b0 of chunk;
  // lanes with bits {1,4,5} == 0 store (8 lanes cover s=0..7).
  const int sq = (((lane >> 3) & 1) << 2) | (((lane >> 2) & 1) << 1) | (lane & 1);
  const bool storer = (lane & 0x32) == 0;
  float* pstore = part + ((w * B_SZ + b) * D_SZ + i) * L_SZ + sq;

  // drain initial compiler loads so vmcnt counting is exact
  asm volatile("" :: "v"(a2), "v"(bw));
  asm volatile("s_waitcnt vmcnt(0)");

  auto compute_chunk = [&](ChunkS& K) {
    float acc[8];
    const float dts[8] = {K.d0[0], K.d0[1], K.d0[2], K.d0[3],
                          K.d1[0], K.d1[1], K.d1[2], K.d1[3]};
    const float dus[8] = {K.u0[0], K.u0[1], K.u0[2], K.u0[3],
                          K.u1[0], K.u1[1], K.u1[2], K.u1[3]};
#pragma unroll
    for (int s = 0; s < 8; ++s) {
      const float e = fexp2(dts[s] * a2);
      h = fmaf(e, h, bw * dus[s]);
      acc[s] = h * K.c[s];
    }
    // fold stage 1: pairing xor15 (row_mirror), side bit3, n2=4
    {
      const bool hi = (lane & 8) != 0;
#pragma unroll
      for (int q = 0; q < 4; ++q) {
        const float keep = hi ? acc[q + 4] : acc[q];
        const float send = hi ? acc[q] : acc[q + 4];
        acc[q] = keep + dpp_mov<0x140>(send);
      }
    }
    // fold stage 2: pairing xor7 (row_half_mirror), side bit2, n2=2
    {
      const bool hi = (lane & 4) != 0;
#pragma unroll
      for (int q = 0; q < 2; ++q) {
        const float keep = hi ? acc[q + 2] : acc[q];
        const float send = hi ? acc[q] : acc[q + 2];
        acc[q] = keep + dpp_mov<0x141>(send);
      }
    }
    // fold stage 3: pairing xor1 (quad_perm [1,0,3,2]), side bit0, n2=1
    {
      const bool hi = (lane & 1) != 0;
      const float keep = hi ? acc[1] : acc[0];
      const float send = hi ? acc[0] : acc[1];
      acc[0] = keep + dpp_mov<0xB1>(send);
    }
    // finish across unused bits {1,4,5}: plain butterflies
    float r = acc[0];
    r += __shfl_xor(r, 2, 64);
    r += __shfl_xor(r, 16, 64);
    r += __shfl_xor(r, 32, 64);
    if (storer) *pstore = r;
    pstore += 8;
  };

  ChunkS K0, K1, K2;
  LOAD_CHUNK(K0, cb0, cb1, cb2, dtB, duB);
  ADV_BASES();
  LOAD_CHUNK(K1, cb0, cb1, cb2, dtB, duB);
  ADV_BASES();
#pragma unroll 1
  for (int it = 0; it < 16; ++it) {
    LOAD_CHUNK(K2, cb0, cb1, cb2, dtB, duB);
    ADV_BASES();
    WAIT_CHUNK(K0);
    compute_chunk(K0);
    LOAD_CHUNK(K0, cb0, cb1, cb2, dtB, duB);
    ADV_BASES();
    WAIT_CHUNK(K1);
    compute_chunk(K1);
    LOAD_CHUNK(K1, cb0, cb1, cb2, dtB, duB);
    ADV_BASES();
    WAIT_CHUNK(K2);
    compute_chunk(K2);
  }
  // 48 chunks computed; the 2 extra prefetched chunks are never waited on
  // and read harmlessly into the adjacent workspace slots.
}

// ---------------------------------------------------------------------------
// Combine + transpose: y[b,l,i] = sum_{w<6} part[w][b][i][l] + u[b,l,i]*D[i]
// ---------------------------------------------------------------------------
__global__ __launch_bounds__(256) void combine_kernel(
    const float* __restrict__ part, const float* __restrict__ u,
    const float* __restrict__ Dv, float* __restrict__ y) {
  __shared__ float T[32][33];
  const int tx = threadIdx.x;
  const int ty0 = threadIdx.y;
  const int b = blockIdx.z;
  const int i0 = blockIdx.y * 32;
  const int l0 = blockIdx.x * 32;
#pragma unroll
  for (int r = 0; r < 4; ++r) {
    const int il = ty0 + 8 * r;
    float s = 0.f;
#pragma unroll
    for (int w = 0; w < 6; ++w)
      s += part[((w * B_SZ + b) * D_SZ + i0 + il) * L_SZ + l0 + tx];
    T[il][tx] = s;
  }
  __syncthreads();
#pragma unroll
  for (int r = 0; r < 4; ++r) {
    const int ll = ty0 + 8 * r;
    const int gi = i0 + tx;
    const int off = (b * L_SZ + l0 + ll) * D_SZ + gi;
    y[off] = fmaf(u[off], Dv[gi], T[tx][ll]);
  }
}

extern "C" void kernel_launch(void* const* d_in, const int* in_sizes, int n_in,
                              void* d_out, int out_size, void* d_ws,
                              size_t ws_size, hipStream_t stream) {
  const float* x = (const float*)d_in[0];
  const float* A_log = (const float*)d_in[1];
  const float* D = (const float*)d_in[2];
  const float* dt_w = (const float*)d_in[3];
  const float* dt_b = (const float*)d_in[4];
  const float* B_w = (const float*)d_in[5];
  const float* C_w = (const float*)d_in[6];
  const float* conv_w = (const float*)d_in[7];
  const float* conv_b = (const float*)d_in[8];
  float* y = (float*)d_out;

  float* ws = (float*)d_ws;
  float* dt = ws;                     // slot 0  [b,l,i]
  float* u = ws + TOT_ELEMS;          // slot 1
  float* Bm = ws + 2 * TOT_ELEMS;     // slot 2
  float* Cm = ws + 3 * TOT_ELEMS;     // slot 3
  float* dt_t = ws + 4 * TOT_ELEMS;   // slot 4  [b,i,l]
  float* dtu_t = ws + 5 * TOT_ELEMS;  // slot 5  [b,i,l]
  float* part = ws + 6 * TOT_ELEMS;   // slots 6..11  [w][b][i][l], w<6
  unsigned short* bfarea = (unsigned short*)(ws + 12 * TOT_ELEMS);
  unsigned short* xbf = bfarea;                 // 294912
  unsigned short* dtwbf = bfarea + 294912;      // 147456
  unsigned short* Bwbf = bfarea + 442368;       // 147456
  unsigned short* Cwbf = bfarea + 589824;       // 147456
  unsigned short* xdblbf = bfarea + 737280;     // 294912

  cvt_bf16_kernel<<<720, 256, 0, stream>>>(x, dt_w, B_w, C_w, xbf, dtwbf, Bwbf, Cwbf);
  mfma_dual_gemm<1><<<dim3(24, 24), 128, 0, stream>>>(xbf, dtwbf, Bwbf, dt_b, dt, xdblbf);
  mfma_dual_gemm<2><<<dim3(24, 24), 128, 0, stream>>>(xdblbf, Bwbf, Cwbf, nullptr, Bm, Cm);
  conv_tr_kernel<<<dim3(L_SZ / 32, D_SZ / 32, B_SZ), dim3(32, 8), 0, stream>>>(
      x, conv_w, conv_b, dt, u, dt_t, dtu_t);
  scan_kernel<<<6 * B_SZ * D_SZ, 64, 0, stream>>>(A_log, dt_t, dtu_t, Bm, Cm, part);
  combine_kernel<<<dim3(L_SZ / 32, D_SZ / 32, B_SZ), dim3(32, 8), 0, stream>>>(
      part, u, D, y);
}